// Round 10
// baseline (523.369 us; speedup 1.0000x reference)
//
#include <hip/hip_runtime.h>

typedef __bf16 bf16x8 __attribute__((ext_vector_type(8)));
typedef __bf16 bf16x4 __attribute__((ext_vector_type(4)));
typedef float  f32x4  __attribute__((ext_vector_type(4)));

#define BATCH 4
#define SEQ 2048
#define DMODEL 1024
#define M_ROWS (BATCH * SEQ)      // 8192
#define NCHUNK 32
#define CLEN 64

// ---------------------------------------------------------------
// async 16B global -> LDS, gfx950
// ---------------------------------------------------------------
__device__ __forceinline__ void gload_lds16(const __bf16* g, __bf16* l) {
    __builtin_amdgcn_global_load_lds(
        (const __attribute__((address_space(1))) void*)g,
        (__attribute__((address_space(3))) void*)l, 16, 0, 0);
}

// ---------------------------------------------------------------
// Weight conversions + Wx transpose (x no longer converted: the
// in_proj GEMM reads f32 x directly and truncates in-register).
//  seg A: in_proj_w -> hi/lo split
//  seg B: out_proj_w -> bf16
//  seg C: x_proj_w (33,1024) -> WxT (1024,36) f32
// ---------------------------------------------------------------
#define GW (2 * DMODEL * DMODEL / 4)      //  524288
#define GO (DMODEL * DMODEL / 4)          //  262144
#define GT (33 * DMODEL)                  //   33792
#define NTOT (GW + GO + GT)               //  820224 = 3204*256

__global__ __launch_bounds__(256) void cvt_all(
    const float* __restrict__ wi, const float* __restrict__ wo,
    const float* __restrict__ wx,
    __bf16* __restrict__ wi_hi, __bf16* __restrict__ wi_lo,
    __bf16* __restrict__ wo_b, float* __restrict__ wxT)
{
    const int g = blockIdx.x * 256 + threadIdx.x;
    if (g < GW) {
        const f32x4 v = *(const f32x4*)(wi + (size_t)g * 4);
        bf16x4 h, l;
#pragma unroll
        for (int j = 0; j < 4; ++j) {
            h[j] = (__bf16)v[j];
            l[j] = (__bf16)(v[j] - (float)h[j]);
        }
        *(bf16x4*)(wi_hi + (size_t)g * 4) = h;
        *(bf16x4*)(wi_lo + (size_t)g * 4) = l;
    } else if (g < GW + GO) {
        const int i = g - GW;
        const f32x4 v = *(const f32x4*)(wo + (size_t)i * 4);
        bf16x4 o;
#pragma unroll
        for (int j = 0; j < 4; ++j) o[j] = (__bf16)v[j];
        *(bf16x4*)(wo_b + (size_t)i * 4) = o;
    } else {
        const int i = g - GW - GO;         // 0 .. 33*1024-1
        const int d = i / 33;
        const int e = i - d * 33;
        wxT[d * 36 + e] = wx[e * DMODEL + d];
    }
}

// ---------------------------------------------------------------
// Tiled GEMM: C[m][n] = sum_k A[m][k]*W[n][k].
// 128x128 tile, BK=32, 4 waves, each a 64x64 quadrant (4x4 accs).
// A: DIRECT global->VGPR (no LDS round-trip). Loads are issued
//    before __syncthreads, whose mandatory vmcnt(0) drains them for
//    free (no pipelining = no FIFO trap of round 8). AT=float: A is
//    read f32 and truncated to bf16 in-register (kills the x_hi pass).
// B: LDS, MFMA-fragment-linear, staged via global_load_lds(16B),
//    wave-static (sub-tile s: lane l = row 16s+(l&15), k (l>>4)*8,
//    at s*512+l*8).
// BSPLIT: C = A_bf16*(Bh+Bl) -- exact weights, truncated activations.
// ---------------------------------------------------------------
template <bool BSPLIT, typename AT>
__global__ __launch_bounds__(256) void gemm_tile(
    const AT* __restrict__ A, const __bf16* __restrict__ Bh,
    const __bf16* __restrict__ Bl,
    float* __restrict__ C, int K, int N)
{
    constexpr int BUF = 128 * 32;                 // 4096 elems = 8 KB
    constexpr int NMAT = BSPLIT ? 2 : 1;          // Bh[,Bl]
    constexpr int NST  = BSPLIT ? 4 : 2;          // B stage ops per wave
    __shared__ alignas(16) __bf16 smem[NMAT * BUF];

    const int lane = threadIdx.x & 63;
    const int wave = threadIdx.x >> 6;
    const int bm = blockIdx.y * 128;
    const int bn = blockIdx.x * 128;
    const int sub_r = lane & 15;
    const int kq = (lane >> 4) * 8;

    __bf16* sBh = smem;
    __bf16* sBl = smem + BUF;                     // BSPLIT only

    // wave-static B staging: i = NST*wave + j, buf = i>>3 (0=Bh,1=Bl), s = i&7
    const __bf16* gS[NST];
    int sS[NST];
#pragma unroll
    for (int j = 0; j < NST; ++j) {
        const int i = NST * wave + j;
        const int buf = i >> 3;
        const int s = i & 7;
        const __bf16* mat = (buf == 0) ? Bh : Bl;
        gS[j] = mat + (size_t)(bn + s * 16 + sub_r) * K + kq;
        sS[j] = buf * BUF + s * 512 + lane * 8;
    }

    // A fragment row bases (this wave's 64-row m-quadrant)
    size_t arow[4];
#pragma unroll
    for (int mi = 0; mi < 4; ++mi)
        arow[mi] = (size_t)(bm + (wave & 1) * 64 + mi * 16 + sub_r) * K + kq;

    f32x4 acc[4][4] = {};
    const int nq = (wave >> 1) * 4;

    for (int k0 = 0; k0 < K; k0 += 32) {
        // ---- stage B (async DMA) + load A (plain global->VGPR) ----
#pragma unroll
        for (int j = 0; j < NST; ++j)
            gload_lds16(gS[j] + k0, smem + sS[j]);

        bf16x8 av[4];
#pragma unroll
        for (int mi = 0; mi < 4; ++mi) {
            if (sizeof(AT) == 4) {
                const float* ap = (const float*)A + arow[mi] + k0;
                const f32x4 v0 = *(const f32x4*)(ap);
                const f32x4 v1 = *(const f32x4*)(ap + 4);
#pragma unroll
                for (int j = 0; j < 4; ++j) {
                    av[mi][j]     = (__bf16)v0[j];
                    av[mi][4 + j] = (__bf16)v1[j];
                }
            } else {
                av[mi] = *(const bf16x8*)((const __bf16*)A + arow[mi] + k0);
            }
        }
        __syncthreads();   // vmcnt(0) drain covers both DMA and A loads

        // ---- compute ----
        bf16x8 bh[4], bl[4];
#pragma unroll
        for (int ni = 0; ni < 4; ++ni) {
            bh[ni] = *(const bf16x8*)(sBh + (nq + ni) * 512 + lane * 8);
            if (BSPLIT) bl[ni] = *(const bf16x8*)(sBl + (nq + ni) * 512 + lane * 8);
        }
#pragma unroll
        for (int mi = 0; mi < 4; ++mi) {
#pragma unroll
            for (int ni = 0; ni < 4; ++ni) {
                if (BSPLIT)
                    acc[mi][ni] = __builtin_amdgcn_mfma_f32_16x16x32_bf16(av[mi], bl[ni], acc[mi][ni], 0, 0, 0);
                acc[mi][ni] = __builtin_amdgcn_mfma_f32_16x16x32_bf16(av[mi], bh[ni], acc[mi][ni], 0, 0, 0);
            }
        }
        __syncthreads();
    }

    // ---- epilogue: D layout row=(l>>4)*4+r, col=l&15 ----
    const int r_off = (lane >> 4) * 4;
    const int cc = lane & 15;
#pragma unroll
    for (int mi = 0; mi < 4; ++mi) {
        const int row0 = bm + (wave & 1) * 64 + mi * 16 + r_off;
#pragma unroll
        for (int ni = 0; ni < 4; ++ni) {
            const int col = bn + (wave >> 1) * 64 + ni * 16 + cc;
#pragma unroll
            for (int r = 0; r < 4; ++r)
                C[(size_t)(row0 + r) * N + col] = acc[mi][ni][r];
        }
    }
}

// ---------------------------------------------------------------
// Fused conv(4)+bias+SiLU -> x_proj(+softplus), WxT (1024,36) f32.
// ---------------------------------------------------------------
__global__ __launch_bounds__(256) void conv_xproj_kernel(
    const float* __restrict__ xz,
    const float* __restrict__ conv_w,
    const float* __restrict__ conv_b,
    const float* __restrict__ WxT,    // (1024, 36)
    float* __restrict__ x_conv,
    float* __restrict__ P)            // (M,33)
{
    const int wave = threadIdx.x >> 6;
    const int lane = threadIdx.x & 63;
    const int m = blockIdx.x * 4 + wave;
    const int l = m & (SEQ - 1);

    float acc[33];
#pragma unroll
    for (int e = 0; e < 33; ++e) acc[e] = 0.f;

    for (int d = lane; d < DMODEL; d += 64) {
        float cacc = conv_b[d];
#pragma unroll
        for (int k = 0; k < 4; ++k) {
            const int ll = l + k - 3;
            if (ll >= 0)
                cacc += xz[(size_t)(m + k - 3) * 2048 + d] * conv_w[d * 4 + k];
        }
        const float xc = cacc / (1.f + __expf(-cacc));   // SiLU
        x_conv[(size_t)m * DMODEL + d] = xc;
        const f32x4* wr = (const f32x4*)(WxT + (size_t)d * 36);
#pragma unroll
        for (int q = 0; q < 8; ++q) {
            const f32x4 w = wr[q];
#pragma unroll
            for (int j = 0; j < 4; ++j) acc[q * 4 + j] += xc * w[j];
        }
        acc[32] += xc * WxT[(size_t)d * 36 + 32];
    }
#pragma unroll
    for (int e = 0; e < 33; ++e) {
        float v = acc[e];
#pragma unroll
        for (int off = 32; off; off >>= 1) v += __shfl_xor(v, off, 64);
        acc[e] = v;
    }
    if (lane == 0) {
        float* out = P + (size_t)m * 33;
        for (int e = 0; e < 32; ++e) out[e] = acc[e];
        const float x = acc[32];
        out[32] = (x > 20.f) ? x : log1pf(expf(x));      // softplus
    }
}

// ---------------------------------------------------------------
// Chunked parallel scan (3 phases).
// ---------------------------------------------------------------
__global__ __launch_bounds__(256) void scan_phase1(
    const float* __restrict__ P,
    const float* __restrict__ xc,
    const float* __restrict__ A_log,
    __bf16* __restrict__ hbuf,
    float* __restrict__ S)
{
    const int d = blockIdx.x * 256 + threadIdx.x;
    const int c = blockIdx.y;
    const int b = blockIdx.z;
    const int l0 = c * CLEN;

    __shared__ float buf[CLEN * 33];
    const float* src = P + (size_t)(b * SEQ + l0) * 33;
    for (int idx = threadIdx.x; idx < CLEN * 33; idx += 256)
        buf[idx] = src[idx];
    __syncthreads();

    if (threadIdx.x == 0 && blockIdx.x == 0) {
        float s = 0.f;
        for (int j = 0; j < CLEN; ++j) s += buf[j * 33 + 32];
        S[b * NCHUNK + c] = s;
    }

    float a[16];
#pragma unroll
    for (int n = 0; n < 16; ++n) a[n] = -__expf(A_log[d * 16 + n]);
    float h[16];
#pragma unroll
    for (int n = 0; n < 16; ++n) h[n] = 0.f;

    for (int j = 0; j < CLEN; ++j) {
        const int m = b * SEQ + l0 + j;
        const float xv = xc[(size_t)m * 1024 + d];
        const float* pp = &buf[j * 33];
        const float delta = pp[32];
        const float dx = delta * xv;
#pragma unroll
        for (int n = 0; n < 16; ++n)
            h[n] = __expf(delta * a[n]) * h[n] + dx * pp[n];
    }

    __bf16* hp = hbuf + ((size_t)(b * NCHUNK + c) * 1024 + d) * 16;
#pragma unroll
    for (int n = 0; n < 16; ++n) hp[n] = (__bf16)h[n];
}

__global__ __launch_bounds__(256) void scan_phase2(
    const float* __restrict__ A_log,
    const float* __restrict__ S,
    __bf16* __restrict__ hbuf)
{
    const int n = threadIdx.x & 15;
    const int d = blockIdx.x * 16 + (threadIdx.x >> 4);
    const int b = blockIdx.y;
    const float a = -__expf(A_log[d * 16 + n]);
    float h = 0.f;
    for (int c = 0; c < NCHUNK; ++c) {
        const size_t off = ((size_t)(b * NCHUNK + c) * 1024 + d) * 16 + n;
        const float he = (float)hbuf[off];
        hbuf[off] = (__bf16)h;
        h = __expf(a * S[b * NCHUNK + c]) * h + he;
    }
}

__global__ __launch_bounds__(256) void scan_phase3(
    const float* __restrict__ P,
    const float* __restrict__ xc,
    const float* __restrict__ xz,
    const float* __restrict__ A_log,
    const float* __restrict__ Dp,
    const __bf16* __restrict__ hbuf,
    __bf16* __restrict__ Y)
{
    const int d = blockIdx.x * 256 + threadIdx.x;
    const int c = blockIdx.y;
    const int b = blockIdx.z;
    const int l0 = c * CLEN;

    __shared__ float buf[CLEN * 33];
    const float* src = P + (size_t)(b * SEQ + l0) * 33;
    for (int idx = threadIdx.x; idx < CLEN * 33; idx += 256)
        buf[idx] = src[idx];
    __syncthreads();

    float a[16];
#pragma unroll
    for (int n = 0; n < 16; ++n) a[n] = -__expf(A_log[d * 16 + n]);
    const float Dv = Dp[d];

    const __bf16* hp = hbuf + ((size_t)(b * NCHUNK + c) * 1024 + d) * 16;
    float h[16];
#pragma unroll
    for (int n = 0; n < 16; ++n) h[n] = (float)hp[n];

    for (int j = 0; j < CLEN; ++j) {
        const int m = b * SEQ + l0 + j;
        const float xv = xc[(size_t)m * 1024 + d];
        const float zv = xz[(size_t)m * 2048 + 1024 + d];
        const float* pp = &buf[j * 33];
        const float delta = pp[32];
        const float dx = delta * xv;
        float y = 0.f;
#pragma unroll
        for (int n = 0; n < 16; ++n) {
            h[n] = __expf(delta * a[n]) * h[n] + dx * pp[n];
            y += h[n] * pp[16 + n];
        }
        y += Dv * xv;
        const float sz = zv / (1.f + __expf(-zv));
        Y[(size_t)m * 1024 + d] = (__bf16)(y * sz);
    }
}

// ---------------------------------------------------------------
extern "C" void kernel_launch(void* const* d_in, const int* in_sizes, int n_in,
                              void* d_out, int out_size, void* d_ws, size_t ws_size,
                              hipStream_t stream) {
    const float* x          = (const float*)d_in[0];
    const float* in_proj_w  = (const float*)d_in[1];
    const float* conv_w     = (const float*)d_in[2];
    const float* conv_b     = (const float*)d_in[3];
    const float* x_proj_w   = (const float*)d_in[4];
    const float* A_log      = (const float*)d_in[5];
    const float* D_param    = (const float*)d_in[6];
    const float* out_proj_w = (const float*)d_in[7];
    float* out = (float*)d_out;

    char* ws = (char*)d_ws;
    // Lifetimes:
    //  t0 cvt_all    writes wi_hi, wi_lo, wo, wxT
    //  t1 gemm<true,float> reads x (f32 input!), wi_* -> writes xz
    //  t2 conv_xproj reads xz, wxT -> writes xconv, params
    //  t3 scan       reads params, xconv, xz -> writes hbuf, y (over wxT; dead)
    //  t4 gemm<false,bf16> reads y, wo -> writes out
    float*  xz     = (float*)(ws);                 // [0, 64M)
    __bf16* wi_hi  = (__bf16*)(ws + 100663296);    // [96M, 100M)
    __bf16* wi_lo  = (__bf16*)(ws + 104857600);    // [100M, 104M)
    float*  xconv  = (float*)(ws + 67108864);      // [64M, 96M)
    float*  params = (float*)(ws + 100663296);     // t2+: over wi_hi head (dead)
    __bf16* hbuf   = (__bf16*)(ws + 101744640);    // t3: 4 MiB
    float*  Sbuf   = (float*)(ws + 105938944);     // t3: 512 B
    __bf16* y      = (__bf16*)(ws + 109051904);    // t3+: 16 MiB
    float*  wxT    = (float*)(ws + 109051904);     // t0-t2: head of y region
    __bf16* wo     = (__bf16*)(ws + 125829120);    // 2 MiB

    // 0) weight conversions + Wx transpose
    cvt_all<<<NTOT / 256, 256, 0, stream>>>(
        in_proj_w, out_proj_w, x_proj_w, wi_hi, wi_lo, wo, wxT);

    // 1) in_proj (M=8192,N=2048,K=1024): xz = bf16(x) @ (Wh+Wl)^T, A read f32
    gemm_tile<true, float><<<dim3(2048 / 128, M_ROWS / 128), 256, 0, stream>>>(
        x, wi_hi, wi_lo, xz, DMODEL, 2048);

    // 2) fused conv+SiLU+x_proj(+softplus)
    conv_xproj_kernel<<<M_ROWS / 4, 256, 0, stream>>>(
        xz, conv_w, conv_b, wxT, xconv, params);

    // 3) chunked parallel scan
    scan_phase1<<<dim3(DMODEL / 256, NCHUNK, BATCH), 256, 0, stream>>>(
        params, xconv, A_log, hbuf, Sbuf);
    scan_phase2<<<dim3(DMODEL / 16, BATCH), 256, 0, stream>>>(
        A_log, Sbuf, hbuf);
    scan_phase3<<<dim3(DMODEL / 256, NCHUNK, BATCH), 256, 0, stream>>>(
        params, xconv, xz, A_log, D_param, hbuf, y);

    // 4) out_proj (M=8192,N=1024,K=1024), plain bf16, A=y direct
    gemm_tile<false, __bf16><<<dim3(1024 / 128, M_ROWS / 128), 256, 0, stream>>>(
        y, wo, nullptr, out, DMODEL, 1024);
}

// Round 11
// 479.427 us; speedup vs baseline: 1.0917x; 1.0917x over previous
//
#include <hip/hip_runtime.h>

typedef __bf16 bf16x8 __attribute__((ext_vector_type(8)));
typedef __bf16 bf16x4 __attribute__((ext_vector_type(4)));
typedef float  f32x4  __attribute__((ext_vector_type(4)));

#define BATCH 4
#define SEQ 2048
#define DMODEL 1024
#define M_ROWS (BATCH * SEQ)      // 8192
#define NCHUNK 32
#define CLEN 64

// ---------------------------------------------------------------
// async 16B global -> LDS, gfx950
// ---------------------------------------------------------------
__device__ __forceinline__ void gload_lds16(const __bf16* g, __bf16* l) {
    __builtin_amdgcn_global_load_lds(
        (const __attribute__((address_space(1))) void*)g,
        (__attribute__((address_space(3))) void*)l, 16, 0, 0);
}

// ---------------------------------------------------------------
// Conversions + Wx transpose, one dispatch (round-9 structure).
//  seg X: x -> bf16 (hi only)
//  seg W: in_proj_w -> hi/lo split
//  seg O: out_proj_w -> bf16
//  seg T: x_proj_w (33,1024) -> WxT (1024,36) f32
// ---------------------------------------------------------------
#define GX (M_ROWS * DMODEL / 4)          // 2097152
#define GW (2 * DMODEL * DMODEL / 4)      //  524288
#define GO (DMODEL * DMODEL / 4)          //  262144
#define GT (33 * DMODEL)                  //   33792
#define NTOT (GX + GW + GO + GT)

__global__ __launch_bounds__(256) void cvt_all(
    const float* __restrict__ x, const float* __restrict__ wi,
    const float* __restrict__ wo, const float* __restrict__ wx,
    __bf16* __restrict__ x_hi,
    __bf16* __restrict__ wi_hi, __bf16* __restrict__ wi_lo,
    __bf16* __restrict__ wo_b, float* __restrict__ wxT)
{
    const int g = blockIdx.x * 256 + threadIdx.x;
    if (g < GX) {
        const f32x4 v = *(const f32x4*)(x + (size_t)g * 4);
        bf16x4 h;
#pragma unroll
        for (int j = 0; j < 4; ++j) h[j] = (__bf16)v[j];
        *(bf16x4*)(x_hi + (size_t)g * 4) = h;
    } else if (g < GX + GW) {
        const int i = g - GX;
        const f32x4 v = *(const f32x4*)(wi + (size_t)i * 4);
        bf16x4 h, l;
#pragma unroll
        for (int j = 0; j < 4; ++j) {
            h[j] = (__bf16)v[j];
            l[j] = (__bf16)(v[j] - (float)h[j]);
        }
        *(bf16x4*)(wi_hi + (size_t)i * 4) = h;
        *(bf16x4*)(wi_lo + (size_t)i * 4) = l;
    } else if (g < GX + GW + GO) {
        const int i = g - GX - GW;
        const f32x4 v = *(const f32x4*)(wo + (size_t)i * 4);
        bf16x4 o;
#pragma unroll
        for (int j = 0; j < 4; ++j) o[j] = (__bf16)v[j];
        *(bf16x4*)(wo_b + (size_t)i * 4) = o;
    } else {
        const int i = g - GX - GW - GO;    // 0 .. 33*1024-1
        const int d = i / 33;
        const int e = i - d * 33;
        wxT[d * 36 + e] = wx[e * DMODEL + d];
    }
}

// ---------------------------------------------------------------
// Tiled GEMM (round-9 structure; measured 127 us / 540 TF-equiv):
// C[m][n] = sum_k A[m][k]*W[n][k]. 128x128 tile, BK=32, 4 waves,
// each a 64x64 quadrant (4x4 accs). All operands LDS-staged via
// global_load_lds(16B), MFMA-fragment-linear, wave-static.
// BSPLIT: C = A*(Bh+Bl) -- exact weights, bf16-truncated activations.
// OUTT: epilogue store type (bf16 for xz, f32 for final out).
// ---------------------------------------------------------------
template <bool BSPLIT, typename OUTT>
__global__ __launch_bounds__(256) void gemm_tile(
    const __bf16* __restrict__ A, const __bf16* __restrict__ Bh,
    const __bf16* __restrict__ Bl,
    OUTT* __restrict__ C, int K, int N)
{
    constexpr int BUF = 128 * 32;                 // 4096 elems = 8 KB
    constexpr int NMAT = BSPLIT ? 3 : 2;          // A,Bh[,Bl]
    constexpr int NST = BSPLIT ? 6 : 4;           // stage ops per wave
    __shared__ alignas(16) __bf16 smem[NMAT * BUF];

    const int lane = threadIdx.x & 63;
    const int wave = threadIdx.x >> 6;
    const int bm = blockIdx.y * 128;
    const int bn = blockIdx.x * 128;
    const int sub_r = lane & 15;
    const int kq = (lane >> 4) * 8;

    __bf16* sA  = smem;
    __bf16* sBh = smem + BUF;
    __bf16* sBl = smem + 2 * BUF;                 // BSPLIT only

    // wave-static staging: i = NST*wave + j, buf = i>>3 (0=A,1=Bh,2=Bl), s = i&7
    const __bf16* gS[NST];
    int sS[NST];
#pragma unroll
    for (int j = 0; j < NST; ++j) {
        const int i = NST * wave + j;
        const int buf = i >> 3;
        const int s = i & 7;
        const __bf16* mat = (buf == 0) ? A : (buf == 1) ? Bh : Bl;
        const int rbase = (buf == 0) ? bm : bn;
        gS[j] = mat + (size_t)(rbase + s * 16 + sub_r) * K + kq;
        sS[j] = buf * BUF + s * 512 + lane * 8;
    }

    f32x4 acc[4][4] = {};
    const int mq = (wave & 1) * 4;
    const int nq = (wave >> 1) * 4;

    for (int k0 = 0; k0 < K; k0 += 32) {
#pragma unroll
        for (int j = 0; j < NST; ++j)
            gload_lds16(gS[j] + k0, smem + sS[j]);
        __syncthreads();

        bf16x8 bh[4], bl[4];
#pragma unroll
        for (int ni = 0; ni < 4; ++ni) {
            bh[ni] = *(const bf16x8*)(sBh + (nq + ni) * 512 + lane * 8);
            if (BSPLIT) bl[ni] = *(const bf16x8*)(sBl + (nq + ni) * 512 + lane * 8);
        }
#pragma unroll
        for (int mi = 0; mi < 4; ++mi) {
            bf16x8 av = *(const bf16x8*)(sA + (mq + mi) * 512 + lane * 8);
#pragma unroll
            for (int ni = 0; ni < 4; ++ni) {
                if (BSPLIT)
                    acc[mi][ni] = __builtin_amdgcn_mfma_f32_16x16x32_bf16(av, bl[ni], acc[mi][ni], 0, 0, 0);
                acc[mi][ni] = __builtin_amdgcn_mfma_f32_16x16x32_bf16(av, bh[ni], acc[mi][ni], 0, 0, 0);
            }
        }
        __syncthreads();
    }

    // ---- epilogue: D layout row=(l>>4)*4+r, col=l&15 ----
    const int r_off = (lane >> 4) * 4;
    const int cc = lane & 15;
#pragma unroll
    for (int mi = 0; mi < 4; ++mi) {
        const int row0 = bm + (wave & 1) * 64 + mi * 16 + r_off;
#pragma unroll
        for (int ni = 0; ni < 4; ++ni) {
            const int col = bn + (wave >> 1) * 64 + ni * 16 + cc;
#pragma unroll
            for (int r = 0; r < 4; ++r)
                C[(size_t)(row0 + r) * N + col] = (OUTT)acc[mi][ni][r];
        }
    }
}

// ---------------------------------------------------------------
// Fused conv(4)+bias+SiLU -> x_proj(+softplus).
// xz is bf16 (M,2048); x_conv written bf16; WxT (1024,36) f32.
// ---------------------------------------------------------------
__global__ __launch_bounds__(256) void conv_xproj_kernel(
    const __bf16* __restrict__ xz,
    const float* __restrict__ conv_w,
    const float* __restrict__ conv_b,
    const float* __restrict__ WxT,
    __bf16* __restrict__ x_conv,
    float* __restrict__ P)            // (M,33)
{
    const int wave = threadIdx.x >> 6;
    const int lane = threadIdx.x & 63;
    const int m = blockIdx.x * 4 + wave;
    const int l = m & (SEQ - 1);

    float acc[33];
#pragma unroll
    for (int e = 0; e < 33; ++e) acc[e] = 0.f;

    for (int d = lane; d < DMODEL; d += 64) {
        float cacc = conv_b[d];
#pragma unroll
        for (int k = 0; k < 4; ++k) {
            const int ll = l + k - 3;
            if (ll >= 0)
                cacc += (float)xz[(size_t)(m + k - 3) * 2048 + d] * conv_w[d * 4 + k];
        }
        const float xc = cacc / (1.f + __expf(-cacc));   // SiLU
        x_conv[(size_t)m * DMODEL + d] = (__bf16)xc;
        const f32x4* wr = (const f32x4*)(WxT + (size_t)d * 36);
#pragma unroll
        for (int q = 0; q < 8; ++q) {
            const f32x4 w = wr[q];
#pragma unroll
            for (int j = 0; j < 4; ++j) acc[q * 4 + j] += xc * w[j];
        }
        acc[32] += xc * WxT[(size_t)d * 36 + 32];
    }
#pragma unroll
    for (int e = 0; e < 33; ++e) {
        float v = acc[e];
#pragma unroll
        for (int off = 32; off; off >>= 1) v += __shfl_xor(v, off, 64);
        acc[e] = v;
    }
    if (lane == 0) {
        float* out = P + (size_t)m * 33;
        for (int e = 0; e < 32; ++e) out[e] = acc[e];
        const float x = acc[32];
        out[32] = (x > 20.f) ? x : log1pf(expf(x));      // softplus
    }
}

// ---------------------------------------------------------------
// Chunked parallel scan (3 phases). xconv/xz/ hbuf are bf16.
// ---------------------------------------------------------------
__global__ __launch_bounds__(256) void scan_phase1(
    const float* __restrict__ P,
    const __bf16* __restrict__ xc,
    const float* __restrict__ A_log,
    __bf16* __restrict__ hbuf,
    float* __restrict__ S)
{
    const int d = blockIdx.x * 256 + threadIdx.x;
    const int c = blockIdx.y;
    const int b = blockIdx.z;
    const int l0 = c * CLEN;

    __shared__ float buf[CLEN * 33];
    const float* src = P + (size_t)(b * SEQ + l0) * 33;
    for (int idx = threadIdx.x; idx < CLEN * 33; idx += 256)
        buf[idx] = src[idx];
    __syncthreads();

    if (threadIdx.x == 0 && blockIdx.x == 0) {
        float s = 0.f;
        for (int j = 0; j < CLEN; ++j) s += buf[j * 33 + 32];
        S[b * NCHUNK + c] = s;
    }

    float a[16];
#pragma unroll
    for (int n = 0; n < 16; ++n) a[n] = -__expf(A_log[d * 16 + n]);
    float h[16];
#pragma unroll
    for (int n = 0; n < 16; ++n) h[n] = 0.f;

    for (int j = 0; j < CLEN; ++j) {
        const int m = b * SEQ + l0 + j;
        const float xv = (float)xc[(size_t)m * 1024 + d];
        const float* pp = &buf[j * 33];
        const float delta = pp[32];
        const float dx = delta * xv;
#pragma unroll
        for (int n = 0; n < 16; ++n)
            h[n] = __expf(delta * a[n]) * h[n] + dx * pp[n];
    }

    __bf16* hp = hbuf + ((size_t)(b * NCHUNK + c) * 1024 + d) * 16;
#pragma unroll
    for (int n = 0; n < 16; ++n) hp[n] = (__bf16)h[n];
}

__global__ __launch_bounds__(256) void scan_phase2(
    const float* __restrict__ A_log,
    const float* __restrict__ S,
    __bf16* __restrict__ hbuf)
{
    const int n = threadIdx.x & 15;
    const int d = blockIdx.x * 16 + (threadIdx.x >> 4);
    const int b = blockIdx.y;
    const float a = -__expf(A_log[d * 16 + n]);
    float h = 0.f;
    for (int c = 0; c < NCHUNK; ++c) {
        const size_t off = ((size_t)(b * NCHUNK + c) * 1024 + d) * 16 + n;
        const float he = (float)hbuf[off];
        hbuf[off] = (__bf16)h;
        h = __expf(a * S[b * NCHUNK + c]) * h + he;
    }
}

__global__ __launch_bounds__(256) void scan_phase3(
    const float* __restrict__ P,
    const __bf16* __restrict__ xc,
    const __bf16* __restrict__ xz,    // z at col 1024+d
    const float* __restrict__ A_log,
    const float* __restrict__ Dp,
    const __bf16* __restrict__ hbuf,
    __bf16* __restrict__ Y)
{
    const int d = blockIdx.x * 256 + threadIdx.x;
    const int c = blockIdx.y;
    const int b = blockIdx.z;
    const int l0 = c * CLEN;

    __shared__ float buf[CLEN * 33];
    const float* src = P + (size_t)(b * SEQ + l0) * 33;
    for (int idx = threadIdx.x; idx < CLEN * 33; idx += 256)
        buf[idx] = src[idx];
    __syncthreads();

    float a[16];
#pragma unroll
    for (int n = 0; n < 16; ++n) a[n] = -__expf(A_log[d * 16 + n]);
    const float Dv = Dp[d];

    const __bf16* hp = hbuf + ((size_t)(b * NCHUNK + c) * 1024 + d) * 16;
    float h[16];
#pragma unroll
    for (int n = 0; n < 16; ++n) h[n] = (float)hp[n];

    for (int j = 0; j < CLEN; ++j) {
        const int m = b * SEQ + l0 + j;
        const float xv = (float)xc[(size_t)m * 1024 + d];
        const float zv = (float)xz[(size_t)m * 2048 + 1024 + d];
        const float* pp = &buf[j * 33];
        const float delta = pp[32];
        const float dx = delta * xv;
        float y = 0.f;
#pragma unroll
        for (int n = 0; n < 16; ++n) {
            h[n] = __expf(delta * a[n]) * h[n] + dx * pp[n];
            y += h[n] * pp[16 + n];
        }
        y += Dv * xv;
        const float sz = zv / (1.f + __expf(-zv));
        Y[(size_t)m * 1024 + d] = (__bf16)(y * sz);
    }
}

// ---------------------------------------------------------------
extern "C" void kernel_launch(void* const* d_in, const int* in_sizes, int n_in,
                              void* d_out, int out_size, void* d_ws, size_t ws_size,
                              hipStream_t stream) {
    const float* x          = (const float*)d_in[0];
    const float* in_proj_w  = (const float*)d_in[1];
    const float* conv_w     = (const float*)d_in[2];
    const float* conv_b     = (const float*)d_in[3];
    const float* x_proj_w   = (const float*)d_in[4];
    const float* A_log      = (const float*)d_in[5];
    const float* D_param    = (const float*)d_in[6];
    const float* out_proj_w = (const float*)d_in[7];
    float* out = (float*)d_out;

    char* ws = (char*)d_ws;
    // Layout (all offsets bytes). Lifetimes:
    //  t0 cvt_all     w: x_hi, wi_hi, wi_lo, wo, wxT
    //  t1 gemm<true>  r: x_hi, wi_* -> w: xz (bf16)
    //  t2 conv_xproj  r: xz, wxT -> w: xconv (over x_hi, dead), params (over wi_hi, dead)
    //  t3 scan        r: params, xconv, xz -> w: hbuf (over wi_lo, dead), Sbuf, y
    //  t4 gemm<false> r: y, wo -> w: out
    __bf16* xz     = (__bf16*)(ws);                // [0, 32M) bf16
    __bf16* x_hi   = (__bf16*)(ws + 33554432);     // [32M, 48M) t0-t1
    __bf16* wi_hi  = (__bf16*)(ws + 50331648);     // [48M, 52M) t0-t1
    __bf16* wi_lo  = (__bf16*)(ws + 54525952);     // [52M, 56M) t0-t1
    __bf16* xconv  = (__bf16*)(ws + 33554432);     // t2+: over x_hi, 16 MB
    float*  params = (float*)(ws + 50331648);      // t2+: over wi_hi, 1.04 MB
    __bf16* hbuf   = (__bf16*)(ws + 54525952);     // t3: over wi_lo, 4 MB
    float*  Sbuf   = (float*)(ws + 58720256);      // [56M, +512)
    float*  wxT    = (float*)(ws + 58724352);      // [56M+4K, +144K) t0-t2
    __bf16* y      = (__bf16*)(ws + 67108864);     // [64M, 80M) t3-t4
    __bf16* wo     = (__bf16*)(ws + 83886080);     // [80M, 82M) t0-t4

    // 0) conversions + Wx transpose
    cvt_all<<<(NTOT + 255) / 256, 256, 0, stream>>>(
        x, in_proj_w, out_proj_w, x_proj_w,
        x_hi, wi_hi, wi_lo, wo, wxT);

    // 1) in_proj (M=8192,N=2048,K=1024): xz = bf16( x_bf16 @ (Wh+Wl)^T )
    gemm_tile<true, __bf16><<<dim3(2048 / 128, M_ROWS / 128), 256, 0, stream>>>(
        x_hi, wi_hi, wi_lo, xz, DMODEL, 2048);

    // 2) fused conv+SiLU+x_proj(+softplus)
    conv_xproj_kernel<<<M_ROWS / 4, 256, 0, stream>>>(
        xz, conv_w, conv_b, wxT, xconv, params);

    // 3) chunked parallel scan
    scan_phase1<<<dim3(DMODEL / 256, NCHUNK, BATCH), 256, 0, stream>>>(
        params, xconv, A_log, hbuf, Sbuf);
    scan_phase2<<<dim3(DMODEL / 16, BATCH), 256, 0, stream>>>(
        A_log, Sbuf, hbuf);
    scan_phase3<<<dim3(DMODEL / 256, NCHUNK, BATCH), 256, 0, stream>>>(
        params, xconv, xz, A_log, D_param, hbuf, y);

    // 4) out_proj (M=8192,N=1024,K=1024), plain bf16, f32 out
    gemm_tile<false, float><<<dim3(1024 / 128, M_ROWS / 128), 256, 0, stream>>>(
        y, wo, nullptr, out, DMODEL, 1024);
}